// Round 4
// baseline (103.034 us; speedup 1.0000x reference)
//
#include <hip/hip_runtime.h>
#include <hip/hip_bf16.h>
#include <math.h>

#define B_   256
#define IN_  512
#define OUT_ 512
#define E_   256
#define DELTA_ 0.1f
#define LN_EPS_ 1e-5f

// ---------------------------------------------------------------------------
// K1: scores[i][o] = pred_emb[i,:]·attn_w[o,:] + attn_b[o]; row-LN over o;
//     sigmoid; wv[i][o] = (W[o][i], |W[o][i]|*sig[i][o]).
// 512 threads (8 waves/CU), 2 i-rows per block, grid 256 (1 block/CU).
// ---------------------------------------------------------------------------
__global__ __launch_bounds__(512)
void k1_scores_ln_sig(const float* __restrict__ pred_emb,
                      const float* __restrict__ attn_w,
                      const float* __restrict__ attn_b,
                      const float* __restrict__ ln_g,
                      const float* __restrict__ ln_b,
                      const float* __restrict__ weights,
                      float2* __restrict__ wv) {
    __shared__ float pe[2][E_];
    __shared__ float red[8][2][2];
    __shared__ float smu[2], srs[2];

    const int t    = threadIdx.x;
    const int lane = t & 63;
    const int wid  = t >> 6;
    const int i0   = blockIdx.x * 2;
    const int o    = t;

    pe[t >> 8][t & 255] = pred_emb[(size_t)(i0 + (t >> 8)) * E_ + (t & 255)];
    __syncthreads();

    const float4* p0 = reinterpret_cast<const float4*>(pe[0]);
    const float4* p1 = reinterpret_cast<const float4*>(pe[1]);
    const float4* wrow = reinterpret_cast<const float4*>(attn_w + (size_t)o * E_);

    float a0 = 0.f, a1 = 0.f;
    #pragma unroll 8
    for (int e4 = 0; e4 < E_ / 4; ++e4) {
        float4 w4 = wrow[e4];
        float4 q0 = p0[e4];
        float4 q1 = p1[e4];
        a0 += q0.x * w4.x + q0.y * w4.y + q0.z * w4.z + q0.w * w4.w;
        a1 += q1.x * w4.x + q1.y * w4.y + q1.z * w4.z + q1.w * w4.w;
    }
    const float bo = attn_b[o];
    a0 += bo;
    a1 += bo;

    {
        float s1 = a0, s2 = a0 * a0;
        float u1 = a1, u2 = a1 * a1;
        #pragma unroll
        for (int off = 32; off > 0; off >>= 1) {
            s1 += __shfl_down(s1, off);
            s2 += __shfl_down(s2, off);
            u1 += __shfl_down(u1, off);
            u2 += __shfl_down(u2, off);
        }
        if (lane == 0) {
            red[wid][0][0] = s1; red[wid][0][1] = s2;
            red[wid][1][0] = u1; red[wid][1][1] = u2;
        }
    }
    __syncthreads();
    if (t < 2) {
        float s1 = 0.f, s2 = 0.f;
        #pragma unroll
        for (int w = 0; w < 8; ++w) { s1 += red[w][t][0]; s2 += red[w][t][1]; }
        float mu  = s1 / (float)OUT_;
        float var = s2 / (float)OUT_ - mu * mu;
        smu[t] = mu;
        srs[t] = rsqrtf(var + LN_EPS_);
    }
    __syncthreads();

    const float g  = ln_g[o];
    const float bb = ln_b[o];
    float z0 = (a0 - smu[0]) * srs[0] * g + bb;
    float z1 = (a1 - smu[1]) * srs[1] * g + bb;
    float sg0 = 1.f / (1.f + expf(-z0));
    float sg1 = 1.f / (1.f + expf(-z1));

    float2 w01 = *reinterpret_cast<const float2*>(weights + (size_t)o * IN_ + i0);
    wv[(size_t)(i0 + 0) * OUT_ + o] = make_float2(w01.x, fabsf(w01.x) * sg0);
    wv[(size_t)(i0 + 1) * OUT_ + o] = make_float2(w01.y, fabsf(w01.y) * sg1);
}

// ---------------------------------------------------------------------------
// K2 (full-K, writes final out — no split-K, no combine kernel):
//   out[b,o] = dot(x[b,:],W[o,:]) + DELTA*(max_i u*v - sum_i u*v), u = x*|x|
// Tile 32b x 16o, grid (32,8)=256 blocks (1/CU), 256 thr = 16 o-lanes x
// 16 b-lanes, each b-lane owns rows bl and bl+16. K chunked by 128 through
// LDS. xs rows padded to 33 float4; ws rows padded to 17 float2. xs reads
// are 16-way same-address broadcast, ws reads 4-way broadcast -> conflict-
// free (G4: broadcasts are free).
// ---------------------------------------------------------------------------
#define K2_CH 128

__global__ __launch_bounds__(256)
void k2_full(const float* __restrict__ x,
             const float2* __restrict__ wv,
             float* __restrict__ out) {
    __shared__ float4 xs4[32 * 33];     // 16.9 KB
    __shared__ float2 ws2[K2_CH * 17];  // 17.4 KB

    const int t  = threadIdx.x;
    const int ot = t & 15;
    const int bl = t >> 4;
    const int o0 = blockIdx.x * 16;
    const int b0 = blockIdx.y * 32;
    const int o  = o0 + ot;

    float d0 = 0.f, s0 = 0.f, m0 = -INFINITY;
    float d1 = 0.f, s1 = 0.f, m1 = -INFINITY;

    for (int c = 0; c < IN_ / K2_CH; ++c) {
        if (c) __syncthreads();   // protect previous chunk's LDS reads
        const int i0 = c * K2_CH;

        // stage x chunk (32 rows x 128 cols)
        #pragma unroll
        for (int k = 0; k < 4; ++k) {
            int p    = t + k * 256;
            int row  = p >> 5;
            int col4 = p & 31;
            xs4[row * 33 + col4] = reinterpret_cast<const float4*>(
                x + (size_t)(b0 + row) * IN_ + i0)[col4];
        }
        // stage wv chunk (128 rows x 16 cols)
        #pragma unroll
        for (int k = 0; k < 8; ++k) {
            int r = bl + 16 * k;
            ws2[r * 17 + ot] = wv[(size_t)(i0 + r) * OUT_ + o0 + ot];
        }
        __syncthreads();

        #pragma unroll 4
        for (int i4 = 0; i4 < K2_CH / 4; ++i4) {
            float4 xa = xs4[(bl +  0) * 33 + i4];
            float4 xb = xs4[(bl + 16) * 33 + i4];
            float2 w0 = ws2[(4 * i4 + 0) * 17 + ot];
            float2 w1 = ws2[(4 * i4 + 1) * 17 + ot];
            float2 w2 = ws2[(4 * i4 + 2) * 17 + ot];
            float2 w3 = ws2[(4 * i4 + 3) * 17 + ot];
            // u = x*|x| : single v_mul with |.| input modifier
            float4 ua = make_float4(xa.x * fabsf(xa.x), xa.y * fabsf(xa.y),
                                    xa.z * fabsf(xa.z), xa.w * fabsf(xa.w));
            float4 ub = make_float4(xb.x * fabsf(xb.x), xb.y * fabsf(xb.y),
                                    xb.z * fabsf(xb.z), xb.w * fabsf(xb.w));
            float pa0 = ua.x * w0.y, pa1 = ua.y * w1.y,
                  pa2 = ua.z * w2.y, pa3 = ua.w * w3.y;
            float pb0 = ub.x * w0.y, pb1 = ub.y * w1.y,
                  pb2 = ub.z * w2.y, pb3 = ub.w * w3.y;
            d0 = fmaf(xa.x, w0.x, d0); d0 = fmaf(xa.y, w1.x, d0);
            d0 = fmaf(xa.z, w2.x, d0); d0 = fmaf(xa.w, w3.x, d0);
            d1 = fmaf(xb.x, w0.x, d1); d1 = fmaf(xb.y, w1.x, d1);
            d1 = fmaf(xb.z, w2.x, d1); d1 = fmaf(xb.w, w3.x, d1);
            s0 += pa0 + pa1 + pa2 + pa3;   // tree-summed by compiler
            s1 += pb0 + pb1 + pb2 + pb3;
            m0 = fmaxf(m0, fmaxf(fmaxf(pa0, pa1), fmaxf(pa2, pa3)));
            m1 = fmaxf(m1, fmaxf(fmaxf(pb0, pb1), fmaxf(pb2, pb3)));
        }
    }

    out[(size_t)(b0 + bl +  0) * OUT_ + o] = d0 + DELTA_ * (m0 - s0);
    out[(size_t)(b0 + bl + 16) * OUT_ + o] = d1 + DELTA_ * (m1 - s1);
}

// ---------------------------------------------------------------------------
extern "C" void kernel_launch(void* const* d_in, const int* in_sizes, int n_in,
                              void* d_out, int out_size, void* d_ws, size_t ws_size,
                              hipStream_t stream) {
    const float* x        = (const float*)d_in[0];
    const float* weights  = (const float*)d_in[1];
    const float* pred_emb = (const float*)d_in[2];
    const float* attn_w   = (const float*)d_in[3];
    const float* attn_b   = (const float*)d_in[4];
    const float* ln_g     = (const float*)d_in[5];
    const float* ln_b     = (const float*)d_in[6];

    float2* wv = (float2*)d_ws;   // IN_*OUT_ float2 = 2 MB scratch

    k1_scores_ln_sig<<<IN_ / 2, 512, 0, stream>>>(
        pred_emb, attn_w, attn_b, ln_g, ln_b, weights, wv);

    k2_full<<<dim3(OUT_ / 16, B_ / 32), 256, 0, stream>>>(x, wv, (float*)d_out);
}